// Round 3
// baseline (1478.260 us; speedup 1.0000x reference)
//
#include <hip/hip_runtime.h>

// Problem constants
#define Bn 4
#define Tn 2048
#define Cn 2048
#define Hn 32
#define Mn 8192              // B*T
#define EPSV 0.00064f

typedef __attribute__((ext_vector_type(8))) short short8;   // 8 x bf16 (4 VGPRs)
typedef __attribute__((ext_vector_type(4))) float f32x4;    // MFMA acc
typedef _Float16 half4 __attribute__((ext_vector_type(4)));

// ---------------- helpers ----------------
__device__ __forceinline__ unsigned short f2bf(float f) {   // round-to-nearest-even f32->bf16
  unsigned int u = __float_as_uint(f);
  u += 0x7fffu + ((u >> 16) & 1u);
  return (unsigned short)(u >> 16);
}
__device__ __forceinline__ float bf2f(unsigned short h) {
  return __uint_as_float(((unsigned int)h) << 16);
}

// ---------------- weight f32 -> bf16 hi/lo split ----------------
// w ~= hi + lo with |w - hi - lo| <= |w| * 2^-16  (kills structured Delta-W error)
__global__ __launch_bounds__(256) void wcast_split_kernel(
    const float* __restrict__ src, unsigned short* __restrict__ hi,
    unsigned short* __restrict__ lo) {
  const size_t e = ((size_t)blockIdx.x * 256 + threadIdx.x) * 4;
  const float4 v = *(const float4*)(src + e);
  ushort4 h, l;
  h.x = f2bf(v.x); h.y = f2bf(v.y); h.z = f2bf(v.z); h.w = f2bf(v.w);
  l.x = f2bf(v.x - bf2f(h.x)); l.y = f2bf(v.y - bf2f(h.y));
  l.z = f2bf(v.z - bf2f(h.z)); l.w = f2bf(v.w - bf2f(h.w));
  *(ushort4*)(hi + e) = h;
  *(ushort4*)(lo + e) = l;
}

// ---------------- token-shift mix (one slot) -> bf16 activation matrix ----------------
__global__ __launch_bounds__(256) void mix_one_kernel(
    const float* __restrict__ x, const float* __restrict__ state,
    const float* __restrict__ tm, unsigned short* __restrict__ xm) {
  const size_t e = ((size_t)blockIdx.x * 256 + threadIdx.x) * 4;
  const int c = (int)(e & (Cn - 1));
  const int t = (int)((e >> 11) & (Tn - 1));
  float4 xv  = *(const float4*)(x + e);
  float4 xxv = (t == 0) ? *(const float4*)(state + c) : *(const float4*)(x + e - Cn);
  float4 m = *(const float4*)(tm + c);
  ushort4 o;
  o.x = f2bf(xv.x * m.x + xxv.x * (1.f - m.x));
  o.y = f2bf(xv.y * m.y + xxv.y * (1.f - m.y));
  o.z = f2bf(xv.z * m.z + xxv.z * (1.f - m.z));
  o.w = f2bf(xv.w * m.w + xxv.w * (1.f - m.w));
  *(ushort4*)(xm + e) = o;
}

// ---------------- bf16 GEMM, 2-pass weight-split: O = A @ (Whi + Wlo)^T ----------------
// M = grid.y*128, N = grid.x*128, K=2048. 256 thr = 4 waves, wave = 64x64 subtile.
// OUT_F16=1 -> f16 output (projections), else f32 (final).
template <int OUT_F16>
__global__ __launch_bounds__(256) void gemm_bt2_kernel(
    const unsigned short* __restrict__ A, const unsigned short* __restrict__ Whi,
    const unsigned short* __restrict__ Wlo, void* __restrict__ Ov) {
  __shared__ unsigned short As [128 * 32];  // 8 KB each; row r at byte r*64, XOR-swizzled 16B slots
  __shared__ unsigned short BsH[128 * 32];
  __shared__ unsigned short BsL[128 * 32];
  const int tid = threadIdx.x;
  const int wv = tid >> 6, ln = tid & 63;
  const int wm = wv >> 1, wn = wv & 1;
  const int m16 = ln & 15, qd = ln >> 4;

  const unsigned short* Ab  = A   + (size_t)blockIdx.y * 128 * Cn;
  const unsigned short* WbH = Whi + (size_t)blockIdx.x * 128 * Cn;
  const unsigned short* WbL = Wlo + (size_t)blockIdx.x * 128 * Cn;

  // staging: per wave 2 insts/array; inst covers 1KB = 16 rows x 64B; lane L -> base + L*16
  const unsigned short* gA[2]; const unsigned short* gBH[2]; const unsigned short* gBL[2];
  int lof[2];
#pragma unroll
  for (int tc = 0; tc < 2; ++tc) {
    int lo = ((wv * 2 + tc) << 10);            // LDS byte base (wave-uniform)
    int r  = (lo >> 6) + (ln >> 2);            // row this lane fills
    int q  = (ln & 3) ^ ((r >> 1) & 3);        // XOR swizzle: slot (ln&3) holds k-quad q
    gA[tc]  = Ab  + (size_t)r * Cn + (q << 3);
    gBH[tc] = WbH + (size_t)r * Cn + (q << 3);
    gBL[tc] = WbL + (size_t)r * Cn + (q << 3);
    lof[tc] = lo;
  }
  // fragment LDS byte offsets (constant across K)
  int aoff[4], boff[4];
#pragma unroll
  for (int mt = 0; mt < 4; ++mt) {
    int r = (wm << 6) + (mt << 4) + m16;
    aoff[mt] = (r << 6) + ((qd ^ ((r >> 1) & 3)) << 4);
  }
#pragma unroll
  for (int nt = 0; nt < 4; ++nt) {
    int r = (wn << 6) + (nt << 4) + m16;
    boff[nt] = (r << 6) + ((qd ^ ((r >> 1) & 3)) << 4);
  }

  f32x4 acc[4][4];
#pragma unroll
  for (int i = 0; i < 4; ++i)
#pragma unroll
    for (int j = 0; j < 4; ++j) acc[i][j] = 0.f;

  for (int k0 = 0; k0 < Cn; k0 += 32) {
#pragma unroll
    for (int tc = 0; tc < 2; ++tc) {
      __builtin_amdgcn_global_load_lds(
          (const __attribute__((address_space(1))) void*)(gA[tc] + k0),
          (__attribute__((address_space(3))) void*)((char*)As + lof[tc]), 16, 0, 0);
      __builtin_amdgcn_global_load_lds(
          (const __attribute__((address_space(1))) void*)(gBH[tc] + k0),
          (__attribute__((address_space(3))) void*)((char*)BsH + lof[tc]), 16, 0, 0);
      __builtin_amdgcn_global_load_lds(
          (const __attribute__((address_space(1))) void*)(gBL[tc] + k0),
          (__attribute__((address_space(3))) void*)((char*)BsL + lof[tc]), 16, 0, 0);
    }
    __syncthreads();
    short8 af[4], bh[4], bl[4];
#pragma unroll
    for (int mt = 0; mt < 4; ++mt) af[mt] = *(const short8*)((const char*)As + aoff[mt]);
#pragma unroll
    for (int nt = 0; nt < 4; ++nt) {
      bh[nt] = *(const short8*)((const char*)BsH + boff[nt]);
      bl[nt] = *(const short8*)((const char*)BsL + boff[nt]);
    }
#pragma unroll
    for (int mt = 0; mt < 4; ++mt)
#pragma unroll
      for (int nt = 0; nt < 4; ++nt) {
        acc[mt][nt] = __builtin_amdgcn_mfma_f32_16x16x32_bf16(af[mt], bh[nt], acc[mt][nt], 0, 0, 0);
        acc[mt][nt] = __builtin_amdgcn_mfma_f32_16x16x32_bf16(af[mt], bl[nt], acc[mt][nt], 0, 0, 0);
      }
    __syncthreads();
  }
  // epilogue: C/D layout col=lane&15, row=quad*4+reg (m89-verified)
#pragma unroll
  for (int mt = 0; mt < 4; ++mt) {
#pragma unroll
    for (int nt = 0; nt < 4; ++nt) {
      int col  = (wn << 6) + (nt << 4) + m16;
      int row0 = (wm << 6) + (mt << 4) + (qd << 2);
      f32x4 cv = acc[mt][nt];
      if constexpr (OUT_F16) {
        _Float16* Ob = (_Float16*)Ov + (size_t)blockIdx.y * 128 * Cn + (size_t)blockIdx.x * 128;
#pragma unroll
        for (int rg = 0; rg < 4; ++rg)
          Ob[(size_t)(row0 + rg) * Cn + col] = (_Float16)cv[rg];
      } else {
        float* Ob = (float*)Ov + (size_t)blockIdx.y * 128 * Cn + (size_t)blockIdx.x * 128;
#pragma unroll
        for (int rg = 0; rg < 4; ++rg)
          Ob[(size_t)(row0 + rg) * Cn + col] = cv[rg];
      }
    }
  }
}

// ---------------- WKV scan + folded base + fused GN*silu(g) ----------------
// out[t] = sum_{j<t} r_t . (k_j * w^(T-1-j)) v_j  +  (r_t * w^t) @ S0  +  (sum_k r_t k_t u_k) v_t
// one block per (b,h); 64 sequential chunks of 32 rows; S, S0 (64x64 f32) in LDS.
__global__ __launch_bounds__(256) void scan_kernel(
    const _Float16* __restrict__ rA, const _Float16* __restrict__ kA,
    const _Float16* __restrict__ vA, const _Float16* __restrict__ gA,
    const float* __restrict__ wkvst, const float* __restrict__ td,
    const float* __restrict__ faaaa, const float* __restrict__ lnw,
    const float* __restrict__ lnb, unsigned short* __restrict__ A2) {
  __shared__ float sR[32][68];
  __shared__ float sK[32][68];    // k * w^(T-1-t)
  __shared__ float sV[32][68];
  __shared__ float sRW[32][68];   // r * w^t (only when chunk active)
  __shared__ float sS[64][68];
  __shared__ float sS0[64][68];
  __shared__ float sAtt[32][36];
  __shared__ float sEw[64];
  __shared__ float sU[64];
  __shared__ float sDotP[32][16];
  __shared__ float sRedM[32][8];
  __shared__ float sRedQ[32][8];
  __shared__ float sMV[32][2];
  __shared__ float sEwMin;
  const int tid = threadIdx.x;
  const int bh = blockIdx.x;
  const int b = bh >> 5, h = bh & 31;
  const size_t colbase = (size_t)b * Tn * Cn + h * 64;
  const _Float16* rG = rA + colbase;
  const _Float16* kG = kA + colbase;
  const _Float16* vG = vA + colbase;
  const _Float16* gG = gA + colbase;
  unsigned short* outG = A2 + colbase;

  if (tid < 64) {
    sEw[tid] = expf(td[h * 64 + tid]);
    sU[tid]  = faaaa[h * 64 + tid];
  }
#pragma unroll
  for (int i = 0; i < 16; ++i) {        // zero S
    int f = tid + i * 256;
    sS[f >> 6][f & 63] = 0.f;
  }
#pragma unroll
  for (int j = 0; j < 4; ++j) {         // stage S0 (64x64)
    int f4 = tid + j * 256;
    int row = f4 >> 4, c4 = (f4 & 15) << 2;
    *(float4*)&sS0[row][c4] = *(const float4*)(wkvst + (size_t)h * 4096 + row * 64 + c4);
  }
  __syncthreads();
  if (tid == 0) {
    float mn = sEw[0];
    for (int i = 1; i < 64; ++i) mn = fminf(mn, sEw[i]);
    sEwMin = mn;
  }
  __syncthreads();

  const int ap  = tid >> 3;             // att/out row (0..31)
  const int aq0 = (tid & 7) << 2;       // att col base
  const int oj0 = (tid & 7) << 3;       // out col base (8 cols)
  const int uk0 = (tid >> 4) << 2;      // S-update k base
  const int uj0 = (tid & 15) << 2;      // S-update j base
  float lw[8], lb[8];
#pragma unroll
  for (int i = 0; i < 8; ++i) { lw[i] = lnw[h * 64 + oj0 + i]; lb[i] = lnb[h * 64 + oj0 + i]; }

  for (int c = 0; c < 64; ++c) {
    const int tb = c << 5;
    const bool active = ((float)tb * sEwMin) < 88.f;   // w^t underflows to 0 past this
    // ---- stage r, k*wback, v + u-dot partials + r*w^t (32 rows x 64 cols) ----
#pragma unroll
    for (int rep = 0; rep < 2; ++rep) {
      int f4 = tid + (rep << 8);
      int row = f4 >> 4;
      int col = (f4 & 15) << 2;
      int t = tb + row;
      size_t off = (size_t)t * Cn + col;
      half4 ru = *(const half4*)(rG + off);
      half4 ku = *(const half4*)(kG + off);
      half4 vu = *(const half4*)(vG + off);
      float4 rv; rv.x = (float)ru.x; rv.y = (float)ru.y; rv.z = (float)ru.z; rv.w = (float)ru.w;
      float4 kf; kf.x = (float)ku.x; kf.y = (float)ku.y; kf.z = (float)ku.z; kf.w = (float)ku.w;
      float4 vf; vf.x = (float)vu.x; vf.y = (float)vu.y; vf.z = (float)vu.z; vf.w = (float)vu.w;
      *(float4*)&sR[row][col] = rv;
      *(float4*)&sV[row][col] = vf;
      float e = (float)(Tn - 1 - t);
      float4 kw;
      kw.x = kf.x * expf(-e * sEw[col + 0]); kw.y = kf.y * expf(-e * sEw[col + 1]);
      kw.z = kf.z * expf(-e * sEw[col + 2]); kw.w = kf.w * expf(-e * sEw[col + 3]);
      *(float4*)&sK[row][col] = kw;
      sDotP[row][f4 & 15] =
          kf.x * rv.x * sU[col + 0] + kf.y * rv.y * sU[col + 1] +
          kf.z * rv.z * sU[col + 2] + kf.w * rv.w * sU[col + 3];
      if (active) {
        float tt = (float)t;
        float4 rw;
        rw.x = rv.x * expf(-tt * sEw[col + 0]); rw.y = rv.y * expf(-tt * sEw[col + 1]);
        rw.z = rv.z * expf(-tt * sEw[col + 2]); rw.w = rv.w * expf(-tt * sEw[col + 3]);
        *(float4*)&sRW[row][col] = rw;
      }
    }
    __syncthreads();
    // ---- att[p][q] = r_p . kw_q, strict mask q < p ----
    {
      float a[4] = {0.f, 0.f, 0.f, 0.f};
      for (int k = 0; k < 64; k += 4) {
        float4 rv = *(const float4*)&sR[ap][k];
#pragma unroll
        for (int qq = 0; qq < 4; ++qq) {
          float4 kv = *(const float4*)&sK[aq0 + qq][k];
          a[qq] += rv.x * kv.x + rv.y * kv.y + rv.z * kv.z + rv.w * kv.w;
        }
      }
#pragma unroll
      for (int qq = 0; qq < 4; ++qq)
        sAtt[ap][aq0 + qq] = ((aq0 + qq) < ap) ? a[qq] : 0.f;
    }
    __syncthreads();
    // ---- out = att@V + R@S (+ RW@S0) + dot*v; bf16-round; GN partials ----
    float y[8];
    {
      float o[8];
#pragma unroll
      for (int i = 0; i < 8; ++i) o[i] = 0.f;
      for (int q = 0; q < 32; ++q) {
        float aw = sAtt[ap][q];
        float4 v0 = *(const float4*)&sV[q][oj0];
        float4 v1 = *(const float4*)&sV[q][oj0 + 4];
        o[0] += aw * v0.x; o[1] += aw * v0.y; o[2] += aw * v0.z; o[3] += aw * v0.w;
        o[4] += aw * v1.x; o[5] += aw * v1.y; o[6] += aw * v1.z; o[7] += aw * v1.w;
      }
      for (int k = 0; k < 64; ++k) {
        float rw = sR[ap][k];
        float4 s0 = *(const float4*)&sS[k][oj0];
        float4 s1 = *(const float4*)&sS[k][oj0 + 4];
        o[0] += rw * s0.x; o[1] += rw * s0.y; o[2] += rw * s0.z; o[3] += rw * s0.w;
        o[4] += rw * s1.x; o[5] += rw * s1.y; o[6] += rw * s1.z; o[7] += rw * s1.w;
      }
      if (active) {
        for (int k = 0; k < 64; ++k) {
          float rw = sRW[ap][k];
          float4 s0 = *(const float4*)&sS0[k][oj0];
          float4 s1 = *(const float4*)&sS0[k][oj0 + 4];
          o[0] += rw * s0.x; o[1] += rw * s0.y; o[2] += rw * s0.z; o[3] += rw * s0.w;
          o[4] += rw * s1.x; o[5] += rw * s1.y; o[6] += rw * s1.z; o[7] += rw * s1.w;
        }
      }
      float dot = 0.f;
#pragma unroll
      for (int s = 0; s < 16; ++s) dot += sDotP[ap][s];
#pragma unroll
      for (int i = 0; i < 8; ++i) o[i] += dot * sV[ap][oj0 + i];
      float sm = 0.f, sq = 0.f;
#pragma unroll
      for (int i = 0; i < 8; ++i) {
        y[i] = bf2f(f2bf(o[i]));
        sm += y[i]; sq += y[i] * y[i];
      }
      sRedM[ap][tid & 7] = sm; sRedQ[ap][tid & 7] = sq;
    }
    __syncthreads();
    if ((tid & 7) == 0) {
      float sm = 0.f, sq = 0.f;
#pragma unroll
      for (int i = 0; i < 8; ++i) { sm += sRedM[ap][i]; sq += sRedQ[ap][i]; }
      float mu = sm * (1.f / 64.f);
      float var = sq * (1.f / 64.f) - mu * mu;
      sMV[ap][0] = mu; sMV[ap][1] = rsqrtf(var + EPSV);
    }
    __syncthreads();
    {
      float mu = sMV[ap][0], rs = sMV[ap][1];
      int t = tb + ap;
      size_t off = (size_t)t * Cn + oj0;
      half4 g0 = *(const half4*)(gG + off);
      half4 g1 = *(const half4*)(gG + off + 4);
      float gv[8] = {(float)g0.x, (float)g0.y, (float)g0.z, (float)g0.w,
                     (float)g1.x, (float)g1.y, (float)g1.z, (float)g1.w};
      unsigned short us[8];
#pragma unroll
      for (int i = 0; i < 8; ++i) {
        float yn = (y[i] - mu) * rs * lw[i] + lb[i];
        float gs = gv[i] / (1.f + expf(-gv[i]));
        us[i] = f2bf(yn * gs);
      }
      ushort4 o0, o1;
      o0.x = us[0]; o0.y = us[1]; o0.z = us[2]; o0.w = us[3];
      o1.x = us[4]; o1.y = us[5]; o1.z = us[6]; o1.w = us[7];
      *(ushort4*)(outG + off) = o0;
      *(ushort4*)(outG + off + 4) = o1;
    }
    // ---- S += Kw^T V (out-phase S reads fenced by the two GN barriers above) ----
    {
      float su[16];
#pragma unroll
      for (int i = 0; i < 4; ++i) {
        float4 s = *(const float4*)&sS[uk0 + i][uj0];
        su[i * 4 + 0] = s.x; su[i * 4 + 1] = s.y; su[i * 4 + 2] = s.z; su[i * 4 + 3] = s.w;
      }
      for (int q = 0; q < 32; ++q) {
        float4 kq = *(const float4*)&sK[q][uk0];
        float4 vq = *(const float4*)&sV[q][uj0];
        su[0]  += kq.x * vq.x; su[1]  += kq.x * vq.y; su[2]  += kq.x * vq.z; su[3]  += kq.x * vq.w;
        su[4]  += kq.y * vq.x; su[5]  += kq.y * vq.y; su[6]  += kq.y * vq.z; su[7]  += kq.y * vq.w;
        su[8]  += kq.z * vq.x; su[9]  += kq.z * vq.y; su[10] += kq.z * vq.z; su[11] += kq.z * vq.w;
        su[12] += kq.w * vq.x; su[13] += kq.w * vq.y; su[14] += kq.w * vq.z; su[15] += kq.w * vq.w;
      }
#pragma unroll
      for (int i = 0; i < 4; ++i) {
        float4 s; s.x = su[i * 4 + 0]; s.y = su[i * 4 + 1]; s.z = su[i * 4 + 2]; s.w = su[i * 4 + 3];
        *(float4*)&sS[uk0 + i][uj0] = s;
      }
    }
    __syncthreads();   // protect sR/sK/sV/sRW vs next staging, sS vs next out-phase
  }
}

// ---------------- launcher ----------------
extern "C" void kernel_launch(void* const* d_in, const int* in_sizes, int n_in,
                              void* d_out, int out_size, void* d_ws, size_t ws_size,
                              hipStream_t stream) {
  const float* x     = (const float*)d_in[0];
  const float* state = (const float*)d_in[1];
  const float* wkvst = (const float*)d_in[2];
  const float* tmk   = (const float*)d_in[3];
  const float* tmv   = (const float*)d_in[4];
  const float* tmr   = (const float*)d_in[5];
  const float* tmg   = (const float*)d_in[6];
  const float* td    = (const float*)d_in[7];
  const float* faaaa = (const float*)d_in[8];
  const float* w_r   = (const float*)d_in[9];
  const float* w_k   = (const float*)d_in[10];
  const float* w_v   = (const float*)d_in[11];
  const float* w_g   = (const float*)d_in[12];
  const float* w_o   = (const float*)d_in[13];
  const float* ln_w  = (const float*)d_in[14];
  const float* ln_b  = (const float*)d_in[15];
  float* out = (float*)d_out;
  char* ws = (char*)d_ws;

  const size_t SZ_W = (size_t)Cn * Cn;   // elems per weight matrix
  // ws layout (bytes), peak 184,549,376 (176 MiB) — below the 200 MiB that ran in R2:
  //  [0, 16.8M)        weight split buffer: Whi | Wlo (reused per GEMM)
  //  [16.8M, 50.3M)    xm bf16 (reused per projection; later aliased by A2 bf16)
  //  [50.3M, 184.5M)   r,k,v,g f16 (33.5M each)
  unsigned short* whi = (unsigned short*)(ws);
  unsigned short* wlo = (unsigned short*)(ws + 8388608);
  unsigned short* xm  = (unsigned short*)(ws + 16777216);
  unsigned short* A2  = (unsigned short*)(ws + 16777216);        // alias: xm dead after G-GEMM
  _Float16* proj      = (_Float16*)(ws + 50331648);
  const size_t SLOT_E = (size_t)Mn * Cn;                          // elems per activation matrix
  _Float16* R = proj;
  _Float16* K = proj + SLOT_E;
  _Float16* V = proj + 2 * SLOT_E;
  _Float16* G = proj + 3 * SLOT_E;

  const float* tms[4]  = {tmr, tmk, tmv, tmg};
  const float* wsrc[4] = {w_r, w_k, w_v, w_g};
  _Float16*    pdst[4] = {R, K, V, G};

  // per-projection pipeline (sequential stream order makes buffer reuse race-free)
  for (int s = 0; s < 4; ++s) {
    wcast_split_kernel<<<dim3(4096), 256, 0, stream>>>(wsrc[s], whi, wlo);
    mix_one_kernel<<<dim3(16384), 256, 0, stream>>>(x, state, tms[s], xm);
    gemm_bt2_kernel<1><<<dim3(16, 64), 256, 0, stream>>>(xm, whi, wlo, pdst[s]);
  }

  scan_kernel<<<dim3(128), 256, 0, stream>>>(R, K, V, G, wkvst, td, faaaa, ln_w, ln_b, A2);

  wcast_split_kernel<<<dim3(4096), 256, 0, stream>>>(w_o, whi, wlo);
  gemm_bt2_kernel<0><<<dim3(16, 64), 256, 0, stream>>>(A2, whi, wlo, out);

  (void)in_sizes; (void)n_in; (void)out_size; (void)ws_size;
}

// Round 4
// 1181.497 us; speedup vs baseline: 1.2512x; 1.2512x over previous
//
#include <hip/hip_runtime.h>

// Problem constants
#define Bn 4
#define Tn 2048
#define Cn 2048
#define Hn 32
#define Mn 8192              // B*T
#define EPSV 0.00064f
#define SEGS 8               // T-segments per (b,h) for the parallel scan

typedef __attribute__((ext_vector_type(8))) short short8;   // 8 x bf16 (4 VGPRs)
typedef __attribute__((ext_vector_type(4))) float f32x4;    // MFMA acc
typedef _Float16 half4 __attribute__((ext_vector_type(4)));

// ---------------- helpers ----------------
__device__ __forceinline__ unsigned short f2bf(float f) {   // round-to-nearest-even f32->bf16
  unsigned int u = __float_as_uint(f);
  u += 0x7fffu + ((u >> 16) & 1u);
  return (unsigned short)(u >> 16);
}
__device__ __forceinline__ float bf2f(unsigned short h) {
  return __uint_as_float(((unsigned int)h) << 16);
}

// ---------------- weight f32 -> bf16 hi/lo split ----------------
// w ~= hi + lo with |w - hi - lo| <= |w| * 2^-16  (kills structured Delta-W error)
__global__ __launch_bounds__(256) void wcast_split_kernel(
    const float* __restrict__ src, unsigned short* __restrict__ hi,
    unsigned short* __restrict__ lo) {
  const size_t e = ((size_t)blockIdx.x * 256 + threadIdx.x) * 4;
  const float4 v = *(const float4*)(src + e);
  ushort4 h, l;
  h.x = f2bf(v.x); h.y = f2bf(v.y); h.z = f2bf(v.z); h.w = f2bf(v.w);
  l.x = f2bf(v.x - bf2f(h.x)); l.y = f2bf(v.y - bf2f(h.y));
  l.z = f2bf(v.z - bf2f(h.z)); l.w = f2bf(v.w - bf2f(h.w));
  *(ushort4*)(hi + e) = h;
  *(ushort4*)(lo + e) = l;
}

// ---------------- token-shift mix (one slot) -> bf16 activation matrix ----------------
__global__ __launch_bounds__(256) void mix_one_kernel(
    const float* __restrict__ x, const float* __restrict__ state,
    const float* __restrict__ tm, unsigned short* __restrict__ xm) {
  const size_t e = ((size_t)blockIdx.x * 256 + threadIdx.x) * 4;
  const int c = (int)(e & (Cn - 1));
  const int t = (int)((e >> 11) & (Tn - 1));
  float4 xv  = *(const float4*)(x + e);
  float4 xxv = (t == 0) ? *(const float4*)(state + c) : *(const float4*)(x + e - Cn);
  float4 m = *(const float4*)(tm + c);
  ushort4 o;
  o.x = f2bf(xv.x * m.x + xxv.x * (1.f - m.x));
  o.y = f2bf(xv.y * m.y + xxv.y * (1.f - m.y));
  o.z = f2bf(xv.z * m.z + xxv.z * (1.f - m.z));
  o.w = f2bf(xv.w * m.w + xxv.w * (1.f - m.w));
  *(ushort4*)(xm + e) = o;
}

// ---------------- bf16 GEMM, 2-pass weight-split: O = A @ (Whi + Wlo)^T ----------------
// M = grid.y*128, N = grid.x*128, K=2048. 256 thr = 4 waves, wave = 64x64 subtile.
// OUT_F16=1 -> f16 output (projections), else f32 (final).
template <int OUT_F16>
__global__ __launch_bounds__(256) void gemm_bt2_kernel(
    const unsigned short* __restrict__ A, const unsigned short* __restrict__ Whi,
    const unsigned short* __restrict__ Wlo, void* __restrict__ Ov) {
  __shared__ unsigned short As [128 * 32];  // 8 KB each; row r at byte r*64, XOR-swizzled 16B slots
  __shared__ unsigned short BsH[128 * 32];
  __shared__ unsigned short BsL[128 * 32];
  const int tid = threadIdx.x;
  const int wv = tid >> 6, ln = tid & 63;
  const int wm = wv >> 1, wn = wv & 1;
  const int m16 = ln & 15, qd = ln >> 4;

  const unsigned short* Ab  = A   + (size_t)blockIdx.y * 128 * Cn;
  const unsigned short* WbH = Whi + (size_t)blockIdx.x * 128 * Cn;
  const unsigned short* WbL = Wlo + (size_t)blockIdx.x * 128 * Cn;

  // staging: per wave 2 insts/array; inst covers 1KB = 16 rows x 64B; lane L -> base + L*16
  const unsigned short* gA[2]; const unsigned short* gBH[2]; const unsigned short* gBL[2];
  int lof[2];
#pragma unroll
  for (int tc = 0; tc < 2; ++tc) {
    int lo = ((wv * 2 + tc) << 10);            // LDS byte base (wave-uniform)
    int r  = (lo >> 6) + (ln >> 2);            // row this lane fills
    int q  = (ln & 3) ^ ((r >> 1) & 3);        // XOR swizzle: slot (ln&3) holds k-quad q
    gA[tc]  = Ab  + (size_t)r * Cn + (q << 3);
    gBH[tc] = WbH + (size_t)r * Cn + (q << 3);
    gBL[tc] = WbL + (size_t)r * Cn + (q << 3);
    lof[tc] = lo;
  }
  // fragment LDS byte offsets (constant across K)
  int aoff[4], boff[4];
#pragma unroll
  for (int mt = 0; mt < 4; ++mt) {
    int r = (wm << 6) + (mt << 4) + m16;
    aoff[mt] = (r << 6) + ((qd ^ ((r >> 1) & 3)) << 4);
  }
#pragma unroll
  for (int nt = 0; nt < 4; ++nt) {
    int r = (wn << 6) + (nt << 4) + m16;
    boff[nt] = (r << 6) + ((qd ^ ((r >> 1) & 3)) << 4);
  }

  f32x4 acc[4][4];
#pragma unroll
  for (int i = 0; i < 4; ++i)
#pragma unroll
    for (int j = 0; j < 4; ++j) acc[i][j] = 0.f;

  for (int k0 = 0; k0 < Cn; k0 += 32) {
#pragma unroll
    for (int tc = 0; tc < 2; ++tc) {
      __builtin_amdgcn_global_load_lds(
          (const __attribute__((address_space(1))) void*)(gA[tc] + k0),
          (__attribute__((address_space(3))) void*)((char*)As + lof[tc]), 16, 0, 0);
      __builtin_amdgcn_global_load_lds(
          (const __attribute__((address_space(1))) void*)(gBH[tc] + k0),
          (__attribute__((address_space(3))) void*)((char*)BsH + lof[tc]), 16, 0, 0);
      __builtin_amdgcn_global_load_lds(
          (const __attribute__((address_space(1))) void*)(gBL[tc] + k0),
          (__attribute__((address_space(3))) void*)((char*)BsL + lof[tc]), 16, 0, 0);
    }
    __syncthreads();
    short8 af[4], bh[4], bl[4];
#pragma unroll
    for (int mt = 0; mt < 4; ++mt) af[mt] = *(const short8*)((const char*)As + aoff[mt]);
#pragma unroll
    for (int nt = 0; nt < 4; ++nt) {
      bh[nt] = *(const short8*)((const char*)BsH + boff[nt]);
      bl[nt] = *(const short8*)((const char*)BsL + boff[nt]);
    }
#pragma unroll
    for (int mt = 0; mt < 4; ++mt)
#pragma unroll
      for (int nt = 0; nt < 4; ++nt) {
        acc[mt][nt] = __builtin_amdgcn_mfma_f32_16x16x32_bf16(af[mt], bh[nt], acc[mt][nt], 0, 0, 0);
        acc[mt][nt] = __builtin_amdgcn_mfma_f32_16x16x32_bf16(af[mt], bl[nt], acc[mt][nt], 0, 0, 0);
      }
    __syncthreads();
  }
  // epilogue: C/D layout col=lane&15, row=quad*4+reg (m89-verified)
#pragma unroll
  for (int mt = 0; mt < 4; ++mt) {
#pragma unroll
    for (int nt = 0; nt < 4; ++nt) {
      int col  = (wn << 6) + (nt << 4) + m16;
      int row0 = (wm << 6) + (mt << 4) + (qd << 2);
      f32x4 cv = acc[mt][nt];
      if constexpr (OUT_F16) {
        _Float16* Ob = (_Float16*)Ov + (size_t)blockIdx.y * 128 * Cn + (size_t)blockIdx.x * 128;
#pragma unroll
        for (int rg = 0; rg < 4; ++rg)
          Ob[(size_t)(row0 + rg) * Cn + col] = (_Float16)cv[rg];
      } else {
        float* Ob = (float*)Ov + (size_t)blockIdx.y * 128 * Cn + (size_t)blockIdx.x * 128;
#pragma unroll
        for (int rg = 0; rg < 4; ++rg)
          Ob[(size_t)(row0 + rg) * Cn + col] = cv[rg];
      }
    }
  }
}

// ---------------- scan pass 1: per-segment state sums ----------------
// segsum[bh][s] = sum over segment s of Kw^T V  (64x64 f32). S held in registers.
// grid (SEGS, 128). Chunks per segment = 64/SEGS.
__global__ __launch_bounds__(256) void seg_sum_kernel(
    const _Float16* __restrict__ kA, const _Float16* __restrict__ vA,
    const float* __restrict__ td, float* __restrict__ segsum) {
  __shared__ float sK[32][68];    // k * w^(T-1-t)
  __shared__ float sV[32][68];
  __shared__ float sEw[64];
  const int tid = threadIdx.x;
  const int seg = blockIdx.x;
  const int bh = blockIdx.y;
  const int b = bh >> 5, h = bh & 31;
  const size_t colbase = (size_t)b * Tn * Cn + h * 64;
  const _Float16* kG = kA + colbase;
  const _Float16* vG = vA + colbase;

  if (tid < 64) sEw[tid] = expf(td[h * 64 + tid]);
  __syncthreads();

  const int uk0 = (tid >> 4) << 2;      // S k base
  const int uj0 = (tid & 15) << 2;      // S j base
  float su[16];
#pragma unroll
  for (int i = 0; i < 16; ++i) su[i] = 0.f;

  const int c0 = seg * (64 / SEGS), c1 = c0 + (64 / SEGS);
  for (int c = c0; c < c1; ++c) {
    const int tb = c << 5;
#pragma unroll
    for (int rep = 0; rep < 2; ++rep) {
      int f4 = tid + (rep << 8);
      int row = f4 >> 4;
      int col = (f4 & 15) << 2;
      int t = tb + row;
      size_t off = (size_t)t * Cn + col;
      half4 ku = *(const half4*)(kG + off);
      half4 vu = *(const half4*)(vG + off);
      float4 vf; vf.x = (float)vu.x; vf.y = (float)vu.y; vf.z = (float)vu.z; vf.w = (float)vu.w;
      *(float4*)&sV[row][col] = vf;
      float e = (float)(Tn - 1 - t);
      float4 kw;
      kw.x = (float)ku.x * expf(-e * sEw[col + 0]);
      kw.y = (float)ku.y * expf(-e * sEw[col + 1]);
      kw.z = (float)ku.z * expf(-e * sEw[col + 2]);
      kw.w = (float)ku.w * expf(-e * sEw[col + 3]);
      *(float4*)&sK[row][col] = kw;
    }
    __syncthreads();
    for (int q = 0; q < 32; ++q) {
      float4 kq = *(const float4*)&sK[q][uk0];
      float4 vq = *(const float4*)&sV[q][uj0];
      su[0]  += kq.x * vq.x; su[1]  += kq.x * vq.y; su[2]  += kq.x * vq.z; su[3]  += kq.x * vq.w;
      su[4]  += kq.y * vq.x; su[5]  += kq.y * vq.y; su[6]  += kq.y * vq.z; su[7]  += kq.y * vq.w;
      su[8]  += kq.z * vq.x; su[9]  += kq.z * vq.y; su[10] += kq.z * vq.z; su[11] += kq.z * vq.w;
      su[12] += kq.w * vq.x; su[13] += kq.w * vq.y; su[14] += kq.w * vq.z; su[15] += kq.w * vq.w;
    }
    __syncthreads();
  }
  float* dst = segsum + ((size_t)bh * SEGS + seg) * 4096;
#pragma unroll
  for (int i = 0; i < 4; ++i) {
    float4 s; s.x = su[i * 4 + 0]; s.y = su[i * 4 + 1]; s.z = su[i * 4 + 2]; s.w = su[i * 4 + 3];
    *(float4*)(dst + (uk0 + i) * 64 + uj0) = s;
  }
}

// ---------------- scan pass 2: segmented WKV + folded base + fused GN*silu(g) ----------------
// out[t] = sum_{j<t} r_t . (k_j * w^(T-1-j)) v_j  +  (r_t * w^t) @ S0  +  (sum_k r_t k_t u_k) v_t
// grid (SEGS, 128): block handles 64/SEGS chunks of 32 rows; initial S = prefix of segsum.
__global__ __launch_bounds__(256) void scan_kernel(
    const _Float16* __restrict__ rA, const _Float16* __restrict__ kA,
    const _Float16* __restrict__ vA, const _Float16* __restrict__ gA,
    const float* __restrict__ wkvst, const float* __restrict__ td,
    const float* __restrict__ faaaa, const float* __restrict__ lnw,
    const float* __restrict__ lnb, const float* __restrict__ segsum,
    unsigned short* __restrict__ A2) {
  __shared__ float sR[32][68];
  __shared__ float sK[32][68];    // k * w^(T-1-t)
  __shared__ float sV[32][68];
  __shared__ float sRW[32][68];   // r * w^t (only when chunk active)
  __shared__ float sS[64][68];
  __shared__ float sS0[64][68];
  __shared__ float sAtt[32][36];
  __shared__ float sEw[64];
  __shared__ float sU[64];
  __shared__ float sDotP[32][16];
  __shared__ float sRedM[32][8];
  __shared__ float sRedQ[32][8];
  __shared__ float sMV[32][2];
  __shared__ float sEwMin;
  const int tid = threadIdx.x;
  const int seg = blockIdx.x;
  const int bh = blockIdx.y;
  const int b = bh >> 5, h = bh & 31;
  const size_t colbase = (size_t)b * Tn * Cn + h * 64;
  const _Float16* rG = rA + colbase;
  const _Float16* kG = kA + colbase;
  const _Float16* vG = vA + colbase;
  const _Float16* gG = gA + colbase;
  unsigned short* outG = A2 + colbase;

  if (tid < 64) {
    sEw[tid] = expf(td[h * 64 + tid]);
    sU[tid]  = faaaa[h * 64 + tid];
  }
  // ---- init sS = prefix sum of preceding segment sums; stage S0 ----
  {
    float4 acc4[4];
#pragma unroll
    for (int j = 0; j < 4; ++j) { acc4[j].x = 0.f; acc4[j].y = 0.f; acc4[j].z = 0.f; acc4[j].w = 0.f; }
    for (int sp = 0; sp < seg; ++sp) {
      const float* basep = segsum + ((size_t)bh * SEGS + sp) * 4096;
#pragma unroll
      for (int j = 0; j < 4; ++j) {
        int f4 = tid + j * 256;
        int row = f4 >> 4, c4 = (f4 & 15) << 2;
        float4 m = *(const float4*)(basep + row * 64 + c4);
        acc4[j].x += m.x; acc4[j].y += m.y; acc4[j].z += m.z; acc4[j].w += m.w;
      }
    }
#pragma unroll
    for (int j = 0; j < 4; ++j) {
      int f4 = tid + j * 256;
      int row = f4 >> 4, c4 = (f4 & 15) << 2;
      *(float4*)&sS[row][c4] = acc4[j];
      *(float4*)&sS0[row][c4] = *(const float4*)(wkvst + (size_t)h * 4096 + row * 64 + c4);
    }
  }
  __syncthreads();
  if (tid == 0) {
    float mn = sEw[0];
    for (int i = 1; i < 64; ++i) mn = fminf(mn, sEw[i]);
    sEwMin = mn;
  }
  __syncthreads();

  const int ap  = tid >> 3;             // att/out row (0..31)
  const int aq0 = (tid & 7) << 2;       // att col base
  const int oj0 = (tid & 7) << 3;       // out col base (8 cols)
  const int uk0 = (tid >> 4) << 2;      // S-update k base
  const int uj0 = (tid & 15) << 2;      // S-update j base
  float lw[8], lb[8];
#pragma unroll
  for (int i = 0; i < 8; ++i) { lw[i] = lnw[h * 64 + oj0 + i]; lb[i] = lnb[h * 64 + oj0 + i]; }

  const int c0 = seg * (64 / SEGS), c1 = c0 + (64 / SEGS);
  for (int c = c0; c < c1; ++c) {
    const int tb = c << 5;
    const bool active = ((float)tb * sEwMin) < 88.f;   // w^t underflows to 0 past this
    // ---- stage r, k*wback, v + u-dot partials + r*w^t (32 rows x 64 cols) ----
#pragma unroll
    for (int rep = 0; rep < 2; ++rep) {
      int f4 = tid + (rep << 8);
      int row = f4 >> 4;
      int col = (f4 & 15) << 2;
      int t = tb + row;
      size_t off = (size_t)t * Cn + col;
      half4 ru = *(const half4*)(rG + off);
      half4 ku = *(const half4*)(kG + off);
      half4 vu = *(const half4*)(vG + off);
      float4 rv; rv.x = (float)ru.x; rv.y = (float)ru.y; rv.z = (float)ru.z; rv.w = (float)ru.w;
      float4 kf; kf.x = (float)ku.x; kf.y = (float)ku.y; kf.z = (float)ku.z; kf.w = (float)ku.w;
      float4 vf; vf.x = (float)vu.x; vf.y = (float)vu.y; vf.z = (float)vu.z; vf.w = (float)vu.w;
      *(float4*)&sR[row][col] = rv;
      *(float4*)&sV[row][col] = vf;
      float e = (float)(Tn - 1 - t);
      float4 kw;
      kw.x = kf.x * expf(-e * sEw[col + 0]); kw.y = kf.y * expf(-e * sEw[col + 1]);
      kw.z = kf.z * expf(-e * sEw[col + 2]); kw.w = kf.w * expf(-e * sEw[col + 3]);
      *(float4*)&sK[row][col] = kw;
      sDotP[row][f4 & 15] =
          kf.x * rv.x * sU[col + 0] + kf.y * rv.y * sU[col + 1] +
          kf.z * rv.z * sU[col + 2] + kf.w * rv.w * sU[col + 3];
      if (active) {
        float tt = (float)t;
        float4 rw;
        rw.x = rv.x * expf(-tt * sEw[col + 0]); rw.y = rv.y * expf(-tt * sEw[col + 1]);
        rw.z = rv.z * expf(-tt * sEw[col + 2]); rw.w = rv.w * expf(-tt * sEw[col + 3]);
        *(float4*)&sRW[row][col] = rw;
      }
    }
    __syncthreads();
    // ---- att[p][q] = r_p . kw_q, strict mask q < p ----
    {
      float a[4] = {0.f, 0.f, 0.f, 0.f};
      for (int k = 0; k < 64; k += 4) {
        float4 rv = *(const float4*)&sR[ap][k];
#pragma unroll
        for (int qq = 0; qq < 4; ++qq) {
          float4 kv = *(const float4*)&sK[aq0 + qq][k];
          a[qq] += rv.x * kv.x + rv.y * kv.y + rv.z * kv.z + rv.w * kv.w;
        }
      }
#pragma unroll
      for (int qq = 0; qq < 4; ++qq)
        sAtt[ap][aq0 + qq] = ((aq0 + qq) < ap) ? a[qq] : 0.f;
    }
    __syncthreads();
    // ---- out = att@V + R@S (+ RW@S0) + dot*v; bf16-round; GN partials ----
    float y[8];
    {
      float o[8];
#pragma unroll
      for (int i = 0; i < 8; ++i) o[i] = 0.f;
      for (int q = 0; q < 32; ++q) {
        float aw = sAtt[ap][q];
        float4 v0 = *(const float4*)&sV[q][oj0];
        float4 v1 = *(const float4*)&sV[q][oj0 + 4];
        o[0] += aw * v0.x; o[1] += aw * v0.y; o[2] += aw * v0.z; o[3] += aw * v0.w;
        o[4] += aw * v1.x; o[5] += aw * v1.y; o[6] += aw * v1.z; o[7] += aw * v1.w;
      }
      for (int k = 0; k < 64; ++k) {
        float rw = sR[ap][k];
        float4 s0 = *(const float4*)&sS[k][oj0];
        float4 s1 = *(const float4*)&sS[k][oj0 + 4];
        o[0] += rw * s0.x; o[1] += rw * s0.y; o[2] += rw * s0.z; o[3] += rw * s0.w;
        o[4] += rw * s1.x; o[5] += rw * s1.y; o[6] += rw * s1.z; o[7] += rw * s1.w;
      }
      if (active) {
        for (int k = 0; k < 64; ++k) {
          float rw = sRW[ap][k];
          float4 s0 = *(const float4*)&sS0[k][oj0];
          float4 s1 = *(const float4*)&sS0[k][oj0 + 4];
          o[0] += rw * s0.x; o[1] += rw * s0.y; o[2] += rw * s0.z; o[3] += rw * s0.w;
          o[4] += rw * s1.x; o[5] += rw * s1.y; o[6] += rw * s1.z; o[7] += rw * s1.w;
        }
      }
      float dot = 0.f;
#pragma unroll
      for (int s = 0; s < 16; ++s) dot += sDotP[ap][s];
#pragma unroll
      for (int i = 0; i < 8; ++i) o[i] += dot * sV[ap][oj0 + i];
      float sm = 0.f, sq = 0.f;
#pragma unroll
      for (int i = 0; i < 8; ++i) {
        y[i] = bf2f(f2bf(o[i]));
        sm += y[i]; sq += y[i] * y[i];
      }
      sRedM[ap][tid & 7] = sm; sRedQ[ap][tid & 7] = sq;
    }
    __syncthreads();
    if ((tid & 7) == 0) {
      float sm = 0.f, sq = 0.f;
#pragma unroll
      for (int i = 0; i < 8; ++i) { sm += sRedM[ap][i]; sq += sRedQ[ap][i]; }
      float mu = sm * (1.f / 64.f);
      float var = sq * (1.f / 64.f) - mu * mu;
      sMV[ap][0] = mu; sMV[ap][1] = rsqrtf(var + EPSV);
    }
    __syncthreads();
    {
      float mu = sMV[ap][0], rs = sMV[ap][1];
      int t = tb + ap;
      size_t off = (size_t)t * Cn + oj0;
      half4 g0 = *(const half4*)(gG + off);
      half4 g1 = *(const half4*)(gG + off + 4);
      float gv[8] = {(float)g0.x, (float)g0.y, (float)g0.z, (float)g0.w,
                     (float)g1.x, (float)g1.y, (float)g1.z, (float)g1.w};
      unsigned short us[8];
#pragma unroll
      for (int i = 0; i < 8; ++i) {
        float yn = (y[i] - mu) * rs * lw[i] + lb[i];
        float gs = gv[i] / (1.f + expf(-gv[i]));
        us[i] = f2bf(yn * gs);
      }
      ushort4 o0, o1;
      o0.x = us[0]; o0.y = us[1]; o0.z = us[2]; o0.w = us[3];
      o1.x = us[4]; o1.y = us[5]; o1.z = us[6]; o1.w = us[7];
      *(ushort4*)(outG + off) = o0;
      *(ushort4*)(outG + off + 4) = o1;
    }
    // ---- S += Kw^T V (out-phase S reads fenced by the two GN barriers above) ----
    {
      float su[16];
#pragma unroll
      for (int i = 0; i < 4; ++i) {
        float4 s = *(const float4*)&sS[uk0 + i][uj0];
        su[i * 4 + 0] = s.x; su[i * 4 + 1] = s.y; su[i * 4 + 2] = s.z; su[i * 4 + 3] = s.w;
      }
      for (int q = 0; q < 32; ++q) {
        float4 kq = *(const float4*)&sK[q][uk0];
        float4 vq = *(const float4*)&sV[q][uj0];
        su[0]  += kq.x * vq.x; su[1]  += kq.x * vq.y; su[2]  += kq.x * vq.z; su[3]  += kq.x * vq.w;
        su[4]  += kq.y * vq.x; su[5]  += kq.y * vq.y; su[6]  += kq.y * vq.z; su[7]  += kq.y * vq.w;
        su[8]  += kq.z * vq.x; su[9]  += kq.z * vq.y; su[10] += kq.z * vq.z; su[11] += kq.z * vq.w;
        su[12] += kq.w * vq.x; su[13] += kq.w * vq.y; su[14] += kq.w * vq.z; su[15] += kq.w * vq.w;
      }
#pragma unroll
      for (int i = 0; i < 4; ++i) {
        float4 s; s.x = su[i * 4 + 0]; s.y = su[i * 4 + 1]; s.z = su[i * 4 + 2]; s.w = su[i * 4 + 3];
        *(float4*)&sS[uk0 + i][uj0] = s;
      }
    }
    __syncthreads();   // protect sR/sK/sV/sRW vs next staging, sS vs next out-phase
  }
}

// ---------------- launcher ----------------
extern "C" void kernel_launch(void* const* d_in, const int* in_sizes, int n_in,
                              void* d_out, int out_size, void* d_ws, size_t ws_size,
                              hipStream_t stream) {
  const float* x     = (const float*)d_in[0];
  const float* state = (const float*)d_in[1];
  const float* wkvst = (const float*)d_in[2];
  const float* tmk   = (const float*)d_in[3];
  const float* tmv   = (const float*)d_in[4];
  const float* tmr   = (const float*)d_in[5];
  const float* tmg   = (const float*)d_in[6];
  const float* td    = (const float*)d_in[7];
  const float* faaaa = (const float*)d_in[8];
  const float* w_r   = (const float*)d_in[9];
  const float* w_k   = (const float*)d_in[10];
  const float* w_v   = (const float*)d_in[11];
  const float* w_g   = (const float*)d_in[12];
  const float* w_o   = (const float*)d_in[13];
  const float* ln_w  = (const float*)d_in[14];
  const float* ln_b  = (const float*)d_in[15];
  float* out = (float*)d_out;
  char* ws = (char*)d_ws;

  const size_t SZ_W = (size_t)Cn * Cn;   // elems per weight matrix
  // ws layout (bytes), peak 201,326,592 (192 MiB) — below the 200 MiB proven in R2:
  //  [0, 16.8M)        weight split buffer: Whi | Wlo (reused per GEMM)
  //  [16.8M, 50.3M)    xm bf16 (reused per projection; later aliased by A2 bf16)
  //  [50.3M, 184.5M)   r,k,v,g f16 (33.5M each)
  //  [184.5M, 201.3M)  segsum f32 (128 bh x 8 seg x 64 x 64)
  unsigned short* whi = (unsigned short*)(ws);
  unsigned short* wlo = (unsigned short*)(ws + 8388608);
  unsigned short* xm  = (unsigned short*)(ws + 16777216);
  unsigned short* A2  = (unsigned short*)(ws + 16777216);        // alias: xm dead after G-GEMM
  _Float16* proj      = (_Float16*)(ws + 50331648);
  float* segsum       = (float*)(ws + 184549376);
  const size_t SLOT_E = (size_t)Mn * Cn;                          // elems per activation matrix
  _Float16* R = proj;
  _Float16* K = proj + SLOT_E;
  _Float16* V = proj + 2 * SLOT_E;
  _Float16* G = proj + 3 * SLOT_E;

  const float* tms[4]  = {tmr, tmk, tmv, tmg};
  const float* wsrc[4] = {w_r, w_k, w_v, w_g};
  _Float16*    pdst[4] = {R, K, V, G};

  // per-projection pipeline (sequential stream order makes buffer reuse race-free)
  for (int s = 0; s < 4; ++s) {
    wcast_split_kernel<<<dim3(4096), 256, 0, stream>>>(wsrc[s], whi, wlo);
    mix_one_kernel<<<dim3(16384), 256, 0, stream>>>(x, state, tms[s], xm);
    gemm_bt2_kernel<1><<<dim3(16, 64), 256, 0, stream>>>(xm, whi, wlo, pdst[s]);
  }

  seg_sum_kernel<<<dim3(SEGS, 128), 256, 0, stream>>>(K, V, td, segsum);
  scan_kernel<<<dim3(SEGS, 128), 256, 0, stream>>>(R, K, V, G, wkvst, td, faaaa,
                                                   ln_w, ln_b, segsum, A2);

  wcast_split_kernel<<<dim3(4096), 256, 0, stream>>>(w_o, whi, wlo);
  gemm_bt2_kernel<0><<<dim3(16, 64), 256, 0, stream>>>(A2, whi, wlo, out);

  (void)in_sizes; (void)n_in; (void)out_size; (void)ws_size;
}